// Round 18
// baseline (461.431 us; speedup 1.0000x reference)
//
#include <hip/hip_runtime.h>

#define NN 300000
#define FF 64
#define EE 2400000
#define FEA 8
#define RAWCAP 131072   // >= 8*129*97 = 100104 (so cluster ids < 2^17)
#define NBUCK 4096      // coarse buckets: cb = cs>>5
#define SUBB 32         // sub-buckets (cs ids) per coarse bucket
#define NSB 512         // scatter blocks
#define TILE ((EE + NSB - 1) / NSB)
#define CAP 1856        // LDS capacity per coarse bucket (mean ~579, +53 sigma)

typedef unsigned long long ull;

__device__ __forceinline__ unsigned fenc(float f) {
  unsigned b = __float_as_uint(f);
  return (b & 0x80000000u) ? ~b : (b | 0x80000000u);
}
__device__ __forceinline__ float fdec(unsigned e) {
  unsigned b = (e & 0x80000000u) ? (e ^ 0x80000000u) : ~e;
  return __uint_as_float(b);
}

__global__ void init_hdr_k(unsigned* hdr) {
  if (threadIdx.x == 0) {
    hdr[0] = 0xFFFFFFFFu; hdr[1] = 0xFFFFFFFFu;  // min enc
    hdr[2] = 0u;          hdr[3] = 0u;           // max enc
    hdr[13] = 0u;                                 // grp_emit ticket
  }
}

__global__ void minmax_k(const float* __restrict__ pos, unsigned* hdr) {
  __shared__ unsigned red[4][4];
  int t = blockIdx.x * blockDim.x + threadIdx.x;
  float mnx = 1e30f, mny = 1e30f, mxx = -1e30f, mxy = -1e30f;
  for (int i = t; i < NN; i += gridDim.x * blockDim.x) {
    float px = pos[i * 3 + 1], py = pos[i * 3 + 2];
    mnx = fminf(mnx, px); mny = fminf(mny, py);
    mxx = fmaxf(mxx, px); mxy = fmaxf(mxy, py);
  }
  for (int o = 1; o < 64; o <<= 1) {
    mnx = fminf(mnx, __shfl_xor(mnx, o));
    mny = fminf(mny, __shfl_xor(mny, o));
    mxx = fmaxf(mxx, __shfl_xor(mxx, o));
    mxy = fmaxf(mxy, __shfl_xor(mxy, o));
  }
  int wid = threadIdx.x >> 6;
  if ((threadIdx.x & 63) == 0) {
    red[wid][0] = fenc(mnx); red[wid][1] = fenc(mny);
    red[wid][2] = fenc(mxx); red[wid][3] = fenc(mxy);
  }
  __syncthreads();
  if (threadIdx.x == 0) {
    unsigned a0 = red[0][0], a1 = red[0][1], a2 = red[0][2], a3 = red[0][3];
    for (int k = 1; k < 4; k++) {
      a0 = min(a0, red[k][0]); a1 = min(a1, red[k][1]);
      a2 = max(a2, red[k][2]); a3 = max(a3, red[k][3]);
    }
    atomicMin(&hdr[0], a0); atomicMin(&hdr[1], a1);
    atomicMax(&hdr[2], a2); atomicMax(&hdr[3], a3);
  }
}

__global__ void dims_k(unsigned* hdr) {
  if (threadIdx.x == 0 && blockIdx.x == 0) {
    float mnx = fdec(hdr[0]), mny = fdec(hdr[1]);
    float mxx = fdec(hdr[2]), mxy = fdec(hdr[3]);
    int d0 = (int)(floorf((mxx - mnx) / 5.0f) + 1.0f);
    int d1 = (int)(floorf((mxy - mny) / 5.0f) + 1.0f);
    hdr[4] = (unsigned)d0;
    hdr[5] = (unsigned)d1;
    ((float*)hdr)[6] = mnx;
    ((float*)hdr)[7] = mny;
  }
}

__global__ void raw_k(const float* __restrict__ pos, const int* __restrict__ batch,
                      const unsigned* __restrict__ hdr, int* __restrict__ cluster,
                      unsigned* __restrict__ flags) {
  int i = blockIdx.x * blockDim.x + threadIdx.x;
  if (i >= NN) return;
  float mnx = ((const float*)hdr)[6], mny = ((const float*)hdr)[7];
  int d0 = (int)hdr[4], d1 = (int)hdr[5];
  int c0 = (int)floorf((pos[i * 3 + 1] - mnx) / 5.0f);
  int c1 = (int)floorf((pos[i * 3 + 2] - mny) / 5.0f);
  int raw = batch[i] * (d0 * d1) + c0 * d1 + c1;
  cluster[i] = raw;
  flags[raw] = 1u;
}

// single-kernel exclusive scan: decoupled lookback (validated r8-r17)
__global__ void __launch_bounds__(256)
scan_lb_k(const unsigned* __restrict__ in, unsigned* __restrict__ out, int ntot,
          unsigned* __restrict__ total_out, ull* __restrict__ desc, int nb) {
  __shared__ unsigned sc[256];
  __shared__ unsigned s_pref;
  int bid = blockIdx.x;
  int base = bid * 1024 + threadIdx.x * 4;
  unsigned v[4]; unsigned s = 0;
#pragma unroll
  for (int k = 0; k < 4; k++) {
    int i = base + k;
    v[k] = (i < ntot) ? in[i] : 0u;
    s += v[k];
  }
  sc[threadIdx.x] = s;
  __syncthreads();
  unsigned xv = s;
  for (int o = 1; o < 256; o <<= 1) {
    unsigned y = (threadIdx.x >= o) ? sc[threadIdx.x - o] : 0u;
    __syncthreads();
    xv += y;
    sc[threadIdx.x] = xv;
    __syncthreads();
  }
  unsigned btot = sc[255];
  if (threadIdx.x == 0) {
    unsigned ex = 0;
    if (bid == 0) {
      atomicExch(&desc[0], (2ULL << 32) | (ull)btot);
    } else {
      atomicExch(&desc[bid], (1ULL << 32) | (ull)btot);
      int p = bid - 1;
      while (true) {
        ull d = atomicAdd(&desc[p], 0ULL);
        unsigned fl = (unsigned)(d >> 32);
        if (fl == 2u) { ex += (unsigned)d; break; }
        if (fl == 1u) { ex += (unsigned)d; --p; }
      }
      atomicExch(&desc[bid], (2ULL << 32) | (ull)(ex + btot));
    }
    s_pref = ex;
    if (total_out && bid == nb - 1) *total_out = ex + btot;
  }
  __syncthreads();
  unsigned run = s_pref + xv - s;
#pragma unroll
  for (int k = 0; k < 4; k++) {
    int i = base + k;
    if (i < ntot) out[i] = run;
    run += v[k];
  }
}

// map raw->cluster id, count members, pack slot r into cluster: (r<<17)|cl
__global__ void node_cnt_k(const unsigned* __restrict__ rank, int* __restrict__ cluster,
                           unsigned* __restrict__ cnt) {
  int i = blockIdx.x * blockDim.x + threadIdx.x;
  if (i >= NN) return;
  unsigned cl = rank[cluster[i]];
  unsigned r = atomicAdd(&cnt[cl], 1u);
  cluster[i] = (int)((r << 17) | cl);
}

// atomic-free: position = node_off[cl] + packed slot
__global__ void node_scatter_k(const int* __restrict__ cluster,
                               const unsigned* __restrict__ node_off,
                               int* __restrict__ nlist) {
  int i = blockIdx.x * blockDim.x + threadIdx.x;
  if (i >= NN) return;
  unsigned c = (unsigned)cluster[i];
  nlist[node_off[c & 0x1FFFFu] + (c >> 17)] = i;
}

// one wave per cluster: gather member rows, fmax in registers, write once.
__global__ void __launch_bounds__(256)
cluster_reduce_k(const float* __restrict__ x, const float* __restrict__ pos,
                 const int* __restrict__ batch, const int* __restrict__ nlist,
                 const unsigned* __restrict__ node_off, const unsigned* __restrict__ hdr,
                 float* __restrict__ out_x, float* __restrict__ out_pos,
                 float* __restrict__ out_batch) {
  int w = (blockIdx.x * blockDim.x + threadIdx.x) >> 6;
  int nw = (gridDim.x * blockDim.x) >> 6;
  int f = threadIdx.x & 63;
  int ncl = (int)hdr[8];
  for (int c = w; c < ncl; c += nw) {
    unsigned o0 = node_off[c];
    int len = (int)(node_off[c + 1] - o0);
    float mx = -1e38f;
    long long ps = 0;
    for (int m = 0; m < len; m++) {
      int nd = nlist[o0 + m];
      mx = fmaxf(mx, x[(size_t)nd * FF + f]);
      if (f < 3) ps += (long long)llrintf(pos[nd * 3 + f] * 65536.0f);
    }
    out_x[(size_t)c * FF + f] = mx;
    if (f < 3) {
      float v = (float)((double)ps / 65536.0 / (double)len);
      if (f > 0) v = floorf(v / 4.0f);
      out_pos[c * 3 + f] = v;
    }
    if (f == 63) out_batch[c] = (float)batch[nlist[o0]];
  }
}

__global__ void node_tail_k(const unsigned* __restrict__ hdr,
                            float* __restrict__ out_x, float* __restrict__ out_pos,
                            float* __restrict__ out_batch) {
  int ncl = (int)hdr[8];
  int total = (NN - ncl) * FF;
  for (int i = blockIdx.x * blockDim.x + threadIdx.x; i < total;
       i += gridDim.x * blockDim.x) {
    int r = ncl + (i >> 6), f = i & 63;
    out_x[(size_t)r * FF + f] = 0.0f;
    if (f < 3) out_pos[r * 3 + f] = 0.0f;
    if (f == 0) out_batch[r] = -1.0f;
  }
}

// ---- edge pipeline ----

__global__ void __launch_bounds__(256)
coarse_cnt_k(const int* __restrict__ ei, const int* __restrict__ cluster,
             unsigned* __restrict__ mat) {
  __shared__ unsigned h[NBUCK];
  for (int i = threadIdx.x; i < NBUCK; i += 256) h[i] = 0u;
  __syncthreads();
  int t0 = blockIdx.x * TILE;
  for (int k = threadIdx.x; k < TILE; k += 256) {
    int t = t0 + k;
    if (t >= EE) break;
    int e0 = __builtin_nontemporal_load(&ei[t]);
    int e1 = __builtin_nontemporal_load(&ei[EE + t]);
    unsigned s = (unsigned)cluster[e0] & 0x1FFFFu;
    unsigned d = (unsigned)cluster[e1] & 0x1FFFFu;
    if (s != d) atomicAdd(&h[s >> 5], 1u);
  }
  __syncthreads();
  for (int i = threadIdx.x; i < NBUCK; i += 256)
    mat[(size_t)blockIdx.x * NBUCK + i] = h[i];
}

__global__ void transpose_k(const unsigned* __restrict__ mat, unsigned* __restrict__ matT) {
  int f = blockIdx.x * blockDim.x + threadIdx.x;
  if (f >= NSB * NBUCK) return;
  int cb = f / NSB, blk = f - cb * NSB;
  matT[f] = mat[(size_t)blk * NBUCK + cb];
}

// keys[p] = (s_low5 << 39) | (d << 22) | eid ; single-writer contiguous chunks
__global__ void __launch_bounds__(256)
coarse_scatter_k(const int* __restrict__ ei, const int* __restrict__ cluster,
                 const unsigned* __restrict__ matT, ull* __restrict__ keys) {
  __shared__ unsigned cur[NBUCK];
  for (int i = threadIdx.x; i < NBUCK; i += 256)
    cur[i] = matT[(size_t)i * NSB + blockIdx.x];
  __syncthreads();
  int t0 = blockIdx.x * TILE;
  for (int k = threadIdx.x; k < TILE; k += 256) {
    int t = t0 + k;
    if (t >= EE) break;
    int e0 = __builtin_nontemporal_load(&ei[t]);
    int e1 = __builtin_nontemporal_load(&ei[EE + t]);
    unsigned s = (unsigned)cluster[e0] & 0x1FFFFu;
    unsigned d = (unsigned)cluster[e1] & 0x1FFFFu;
    if (s == d) continue;
    unsigned p = atomicAdd(&cur[s >> 5], 1u);
    keys[p] = ((ull)(s & 31u) << 39) | ((ull)d << 22) | (unsigned)t;
  }
}

// FUSED grouping+emit (r14 structure: per-element flat loops = max TLP).
// Fused b32 scan for head+rank; ~19.2KB LDS -> 8 blocks/CU (wave cap).
__global__ void __launch_bounds__(256)
grp_emit_k(const ull* __restrict__ keys, const unsigned* __restrict__ matT,
           unsigned* __restrict__ hdr, ull* __restrict__ desc,
           const float* __restrict__ ea,
           float* __restrict__ out_src, float* __restrict__ out_dst,
           float* __restrict__ out_ea) {
  __shared__ unsigned cd17[CAP];                 // d (17b), the scan key
  __shared__ unsigned eidj[CAP];                 // eid (22b) | j<<22
  __shared__ unsigned short hr[CAP];             // rank | 0x8000 if head
  __shared__ unsigned h[SUBB], pre[SUBB + 1], cur[SUBB], hc[SUBB], hpre[SUBB];
  __shared__ unsigned sG, sBase, sCnt, sBid;
  int tid = threadIdx.x;
  // ticket: monotone bucket acquisition -> lookback progress guaranteed
  if (tid == 0) sBid = atomicAdd(&hdr[13], 1u);
  __syncthreads();
  int cb = (int)sBid;
  unsigned start = matT[(size_t)cb * NSB];
  unsigned end = (cb == NBUCK - 1) ? hdr[11] : matT[(size_t)(cb + 1) * NSB];
  int len = (int)(end - start);
  bool lds = (len <= CAP);
  unsigned G = 0;

  if (len > 0 && lds) {
    if (tid < SUBB) { h[tid] = 0u; hc[tid] = 0u; }
    __syncthreads();
    for (int i = tid; i < len; i += 256)
      atomicAdd(&h[(unsigned)(keys[start + i] >> 39) & (SUBB - 1u)], 1u);
    __syncthreads();
    if (tid == 0) {
      unsigned run = 0;
      for (int j = 0; j < SUBB; j++) { pre[j] = run; run += h[j]; }
      pre[SUBB] = run;
    }
    __syncthreads();
    if (tid < SUBB) cur[tid] = pre[tid];
    __syncthreads();
    for (int i = tid; i < len; i += 256) {
      ull v = keys[start + i];                 // L2-hot second read
      unsigned j = (unsigned)(v >> 39) & (SUBB - 1u);
      unsigned p = atomicAdd(&cur[j], 1u);
      cd17[p] = (unsigned)((v >> 22) & 0x1FFFFULL);
      eidj[p] = (unsigned)(v & 0x3FFFFFULL) | (j << 22);
    }
    __syncthreads();
    // fused pass: head + cntSmaller in ONE b32 scan per element
    for (int i = tid; i < len; i += 256) {
      unsigned j = eidj[i] >> 22;
      unsigned mine = cd17[i];
      int lo = (int)pre[j], hi = (int)pre[j + 1];
      unsigned cntSm = 0, eqB = 0;
      for (int q = lo; q < hi; ++q) {
        unsigned c = cd17[q];
        cntSm += (c < mine) ? 1u : 0u;
        eqB += (c == mine && q < i) ? 1u : 0u;
      }
      bool head = (eqB == 0u);
      hr[i] = (unsigned short)(cntSm | (head ? 0x8000u : 0u));
      if (head) atomicAdd(&hc[j], 1u);
    }
    __syncthreads();
    // rare fixup: non-singleton sub-buckets need rank among DISTINCT cds
    for (int i = tid; i < len; i += 256) {
      unsigned j = eidj[i] >> 22;
      if (hc[j] == pre[j + 1] - pre[j]) continue;       // all distinct
      if (!(hr[i] & 0x8000u)) continue;
      unsigned mine = cd17[i];
      unsigned r = 0;
      for (int q = (int)pre[j]; q < (int)pre[j + 1]; ++q)
        r += ((hr[q] & 0x8000u) && cd17[q] < mine) ? 1u : 0u;
      hr[i] = (unsigned short)(0x8000u | r);
    }
    __syncthreads();
    if (tid == 0) {
      unsigned run = 0;
      for (int j = 0; j < SUBB; j++) { hpre[j] = run; run += hc[j]; }
      sG = run;
    }
    __syncthreads();
    G = sG;
  } else if (len > 0) {
    // insurance (len > CAP, unreachable for this data): per-sub-bucket staging
    if (tid == 0) sG = 0;
    __syncthreads();
    for (int j = 0; j < SUBB; j++) {
      if (tid == 0) sCnt = 0;
      __syncthreads();
      for (int i = tid; i < len; i += 256) {
        ull v = keys[start + i];
        if (((unsigned)(v >> 39) & (SUBB - 1u)) == (unsigned)j) {
          unsigned p = atomicAdd(&sCnt, 1u);
          if (p < CAP) {
            cd17[p] = (unsigned)((v >> 22) & 0x1FFFFULL);
            eidj[p] = (unsigned)(v & 0x3FFFFFULL);
          }
        }
      }
      __syncthreads();
      int sl = min((int)sCnt, CAP);
      for (int i = tid; i < sl; i += 256) {
        unsigned mine = cd17[i];
        bool head = true;
        for (int q = 0; q < i; ++q)
          head = head && (cd17[q] != mine);
        hr[i] = head ? 0x8000u : 0u;
      }
      __syncthreads();
      if (tid == 0) {
        unsigned c = 0;
        for (int q = 0; q < sl; ++q) c += (hr[q] & 0x8000u) ? 1u : 0u;
        hc[j] = c; hpre[j] = sG; sG += c;
      }
      __syncthreads();
    }
    G = sG;
  }

  // inline decoupled lookback over coarse buckets -> global row base
  if (tid == 0) {
    unsigned ex = 0;
    if (cb == 0) {
      atomicExch(&desc[0], (2ULL << 32) | (ull)G);
    } else {
      atomicExch(&desc[cb], (1ULL << 32) | (ull)G);
      int p = cb - 1;
      while (true) {
        ull d = atomicAdd(&desc[p], 0ULL);
        unsigned fl = (unsigned)(d >> 32);
        if (fl == 2u) { ex += (unsigned)d; break; }
        if (fl == 1u) { ex += (unsigned)d; --p; }
      }
      atomicExch(&desc[cb], (2ULL << 32) | (ull)(ex + G));
    }
    sBase = ex;
    if (cb == NBUCK - 1) hdr[12] = ex + G;   // total groups for tail_fill
  }
  __syncthreads();
  unsigned base = sBase;
  if (len <= 0) return;

  if (lds) {
    // flat emit: max gather concurrency, rank from hr lookup
    for (int i = tid; i < len; i += 256) {
      unsigned hrv = hr[i];
      if (!(hrv & 0x8000u)) continue;
      unsigned ej = eidj[i];
      unsigned j = ej >> 22;
      unsigned mine = cd17[i];
      const float4* p4 = (const float4*)&ea[(size_t)(ej & 0x3FFFFFu) * FEA];
      float4 a0 = p4[0], a1 = p4[1];
      if (hc[j] != pre[j + 1] - pre[j]) {        // non-singleton sub-bucket
        for (unsigned q = pre[j]; q < pre[j + 1]; ++q) {
          if (q == (unsigned)i) continue;
          if (cd17[q] == mine) {
            const float4* q4 = (const float4*)&ea[(size_t)(eidj[q] & 0x3FFFFFu) * FEA];
            float4 b0 = q4[0], b1 = q4[1];
            a0.x += b0.x; a0.y += b0.y; a0.z += b0.z; a0.w += b0.w;
            a1.x += b1.x; a1.y += b1.y; a1.z += b1.z; a1.w += b1.w;
          }
        }
      }
      unsigned row = base + hpre[j] + (hrv & 0x7FFFu);
      out_src[row] = (float)(cb * SUBB + (int)j);
      out_dst[row] = (float)mine;
      float4* o = (float4*)&out_ea[(size_t)row * FEA];
      o[0] = a0; o[1] = a1;
    }
  } else {
    // insurance emit: redo per-sub-bucket staging and emit
    for (int j = 0; j < SUBB; j++) {
      if (tid == 0) sCnt = 0;
      __syncthreads();
      for (int i = tid; i < len; i += 256) {
        ull v = keys[start + i];
        if (((unsigned)(v >> 39) & (SUBB - 1u)) == (unsigned)j) {
          unsigned p = atomicAdd(&sCnt, 1u);
          if (p < CAP) {
            cd17[p] = (unsigned)((v >> 22) & 0x1FFFFULL);
            eidj[p] = (unsigned)(v & 0x3FFFFFULL);
          }
        }
      }
      __syncthreads();
      int sl = min((int)sCnt, CAP);
      for (int i = tid; i < sl; i += 256) {
        unsigned mine = cd17[i];
        bool head = true;
        for (int q = 0; q < i; ++q)
          head = head && (cd17[q] != mine);
        hr[i] = head ? 0x8000u : 0u;
      }
      __syncthreads();
      for (int i = tid; i < sl; i += 256) {
        if (!(hr[i] & 0x8000u)) continue;
        unsigned mine = cd17[i];
        unsigned r = 0;
        for (int q = 0; q < sl; ++q)
          r += ((hr[q] & 0x8000u) && cd17[q] < mine) ? 1u : 0u;
        const float4* p4 = (const float4*)&ea[(size_t)(eidj[i] & 0x3FFFFFu) * FEA];
        float4 a0 = p4[0], a1 = p4[1];
        if (hc[j] != (unsigned)sl) {
          for (int q = 0; q < sl; ++q) {
            if (q == i) continue;
            if (cd17[q] == mine) {
              const float4* q4 = (const float4*)&ea[(size_t)(eidj[q] & 0x3FFFFFu) * FEA];
              float4 b0 = q4[0], b1 = q4[1];
              a0.x += b0.x; a0.y += b0.y; a0.z += b0.z; a0.w += b0.w;
              a1.x += b1.x; a1.y += b1.y; a1.z += b1.z; a1.w += b1.w;
            }
          }
        }
        unsigned row = base + hpre[j] + r;
        out_src[row] = (float)(cb * SUBB + j);
        out_dst[row] = (float)mine;
        float4* o = (float4*)&out_ea[(size_t)row * FEA];
        o[0] = a0; o[1] = a1;
      }
      __syncthreads();
    }
  }
}

// rows >= T get -1/-1 and zero ea (T = hdr[12] from grp_emit)
__global__ void tail_fill_k(const unsigned* __restrict__ hdr,
                            float* __restrict__ out_src, float* __restrict__ out_dst,
                            float* __restrict__ out_ea) {
  int T = (int)hdr[12];
  for (int t = T + blockIdx.x * blockDim.x + threadIdx.x; t < EE;
       t += gridDim.x * blockDim.x) {
    out_src[t] = -1.0f;
    out_dst[t] = -1.0f;
    float4 z = make_float4(0.f, 0.f, 0.f, 0.f);
    float4* o = (float4*)&out_ea[(size_t)t * FEA];
    o[0] = z; o[1] = z;
  }
}

extern "C" void kernel_launch(void* const* d_in, const int* in_sizes, int n_in,
                              void* d_out, int out_size, void* d_ws, size_t ws_size,
                              hipStream_t stream) {
  const float* x   = (const float*)d_in[0];
  const float* pos = (const float*)d_in[1];
  const int* batch = (const int*)d_in[2];
  const int* ei    = (const int*)d_in[3];
  const float* ea  = (const float*)d_in[4];
  float* out = (float*)d_out;

  const size_t OX = 0;
  const size_t OP = (size_t)NN * FF;
  const size_t OB = OP + (size_t)NN * 3;
  const size_t OE = OB + (size_t)NN;
  const size_t OA = OE + (size_t)2 * EE;

  char* w = (char*)d_ws;
  size_t woff = 0;
  auto alloc = [&](size_t bytes) -> void* {
    void* p = w + woff;
    woff += (bytes + 255) & ~(size_t)255;
    return p;
  };
  // zeroed region (one memset)
  unsigned* rank    = (unsigned*)alloc((size_t)RAWCAP * 4);
  unsigned* cnt     = (unsigned*)alloc((size_t)(NN + 1) * 4);
  ull* desc0        = (ull*)alloc(4096 * 8);
  ull* desc1        = (ull*)alloc(4096 * 8);
  ull* desc2        = (ull*)alloc(4096 * 8);
  ull* desc3        = (ull*)alloc(4096 * 8);
  size_t zero_bytes = woff;
  // written-before-read region
  int* cluster      = (int*)alloc((size_t)NN * 4);
  int* nlist        = (int*)alloc((size_t)NN * 4);
  unsigned* node_off= (unsigned*)alloc((size_t)(NN + 2) * 4);
  unsigned* mat     = (unsigned*)alloc((size_t)NSB * NBUCK * 4);
  unsigned* matT    = (unsigned*)alloc((size_t)NSB * NBUCK * 4);
  unsigned* hdr     = (unsigned*)alloc(256);
  ull* keys         = (ull*)alloc((size_t)EE * 8);

  hipMemsetAsync(d_ws, 0, zero_bytes, stream);

  init_hdr_k<<<1, 64, 0, stream>>>(hdr);
  minmax_k<<<128, 256, 0, stream>>>(pos, hdr);
  dims_k<<<1, 64, 0, stream>>>(hdr);
  raw_k<<<(NN + 255) / 256, 256, 0, stream>>>(pos, batch, hdr, cluster, rank);

  auto scan1 = [&](const unsigned* in_, unsigned* out_, int ntot,
                   unsigned* total_out, ull* d_) {
    int nb = (ntot + 1023) / 1024;
    scan_lb_k<<<nb, 256, 0, stream>>>(in_, out_, ntot, total_out, d_, nb);
  };
  scan1(rank, rank, RAWCAP, hdr + 8, desc0);   // rank[raw]=cluster id; total->ncl

  node_cnt_k<<<(NN + 255) / 256, 256, 0, stream>>>(rank, cluster, cnt);
  scan1(cnt, node_off, NN + 1, nullptr, desc1);
  node_scatter_k<<<(NN + 255) / 256, 256, 0, stream>>>(cluster, node_off, nlist);
  cluster_reduce_k<<<2048, 256, 0, stream>>>(x, pos, batch, nlist, node_off, hdr,
                                             out + OX, out + OP, out + OB);
  node_tail_k<<<2048, 256, 0, stream>>>(hdr, out + OX, out + OP, out + OB);

  coarse_cnt_k<<<NSB, 256, 0, stream>>>(ei, cluster, mat);
  transpose_k<<<(NSB * NBUCK + 255) / 256, 256, 0, stream>>>(mat, matT);
  scan1(matT, matT, NSB * NBUCK, hdr + 11, desc2);   // chunk offsets; total->Etot
  coarse_scatter_k<<<NSB, 256, 0, stream>>>(ei, cluster, matT, keys);
  grp_emit_k<<<NBUCK, 256, 0, stream>>>(keys, matT, hdr, desc3, ea,
                                        out + OE, out + OE + EE, out + OA);
  tail_fill_k<<<512, 256, 0, stream>>>(hdr, out + OE, out + OE + EE, out + OA);
}

// Round 19
// 423.579 us; speedup vs baseline: 1.0894x; 1.0894x over previous
//
#include <hip/hip_runtime.h>

#define NN 300000
#define FF 64
#define EE 2400000
#define FEA 8
#define RAWCAP 131072   // >= 8*129*97 = 100104 (so cluster ids < 2^17)
#define NBUCK 4096      // coarse buckets: cb = cs>>5
#define SUBB 32         // sub-buckets (cs ids) per coarse bucket
#define NSB 512         // scatter blocks
#define TILE ((EE + NSB - 1) / NSB)
#define CAP 2048        // LDS capacity per coarse bucket (mean ~586, 3.5x margin)

typedef unsigned long long ull;

__device__ __forceinline__ unsigned fenc(float f) {
  unsigned b = __float_as_uint(f);
  return (b & 0x80000000u) ? ~b : (b | 0x80000000u);
}
__device__ __forceinline__ float fdec(unsigned e) {
  unsigned b = (e & 0x80000000u) ? (e ^ 0x80000000u) : ~e;
  return __uint_as_float(b);
}

__global__ void init_hdr_k(unsigned* hdr) {
  if (threadIdx.x == 0) {
    hdr[0] = 0xFFFFFFFFu; hdr[1] = 0xFFFFFFFFu;  // min enc
    hdr[2] = 0u;          hdr[3] = 0u;           // max enc
    hdr[13] = 0u;                                 // grp_emit ticket
  }
}

__global__ void minmax_k(const float* __restrict__ pos, unsigned* hdr) {
  __shared__ unsigned red[4][4];
  int t = blockIdx.x * blockDim.x + threadIdx.x;
  float mnx = 1e30f, mny = 1e30f, mxx = -1e30f, mxy = -1e30f;
  for (int i = t; i < NN; i += gridDim.x * blockDim.x) {
    float px = pos[i * 3 + 1], py = pos[i * 3 + 2];
    mnx = fminf(mnx, px); mny = fminf(mny, py);
    mxx = fmaxf(mxx, px); mxy = fmaxf(mxy, py);
  }
  for (int o = 1; o < 64; o <<= 1) {
    mnx = fminf(mnx, __shfl_xor(mnx, o));
    mny = fminf(mny, __shfl_xor(mny, o));
    mxx = fmaxf(mxx, __shfl_xor(mxx, o));
    mxy = fmaxf(mxy, __shfl_xor(mxy, o));
  }
  int wid = threadIdx.x >> 6;
  if ((threadIdx.x & 63) == 0) {
    red[wid][0] = fenc(mnx); red[wid][1] = fenc(mny);
    red[wid][2] = fenc(mxx); red[wid][3] = fenc(mxy);
  }
  __syncthreads();
  if (threadIdx.x == 0) {
    unsigned a0 = red[0][0], a1 = red[0][1], a2 = red[0][2], a3 = red[0][3];
    for (int k = 1; k < 4; k++) {
      a0 = min(a0, red[k][0]); a1 = min(a1, red[k][1]);
      a2 = max(a2, red[k][2]); a3 = max(a3, red[k][3]);
    }
    atomicMin(&hdr[0], a0); atomicMin(&hdr[1], a1);
    atomicMax(&hdr[2], a2); atomicMax(&hdr[3], a3);
  }
}

__global__ void dims_k(unsigned* hdr) {
  if (threadIdx.x == 0 && blockIdx.x == 0) {
    float mnx = fdec(hdr[0]), mny = fdec(hdr[1]);
    float mxx = fdec(hdr[2]), mxy = fdec(hdr[3]);
    int d0 = (int)(floorf((mxx - mnx) / 5.0f) + 1.0f);
    int d1 = (int)(floorf((mxy - mny) / 5.0f) + 1.0f);
    hdr[4] = (unsigned)d0;
    hdr[5] = (unsigned)d1;
    ((float*)hdr)[6] = mnx;
    ((float*)hdr)[7] = mny;
  }
}

__global__ void raw_k(const float* __restrict__ pos, const int* __restrict__ batch,
                      const unsigned* __restrict__ hdr, int* __restrict__ cluster,
                      unsigned* __restrict__ flags) {
  int i = blockIdx.x * blockDim.x + threadIdx.x;
  if (i >= NN) return;
  float mnx = ((const float*)hdr)[6], mny = ((const float*)hdr)[7];
  int d0 = (int)hdr[4], d1 = (int)hdr[5];
  int c0 = (int)floorf((pos[i * 3 + 1] - mnx) / 5.0f);
  int c1 = (int)floorf((pos[i * 3 + 2] - mny) / 5.0f);
  int raw = batch[i] * (d0 * d1) + c0 * d1 + c1;
  cluster[i] = raw;
  flags[raw] = 1u;
}

// single-kernel exclusive scan: decoupled lookback (validated r8-r17)
__global__ void __launch_bounds__(256)
scan_lb_k(const unsigned* __restrict__ in, unsigned* __restrict__ out, int ntot,
          unsigned* __restrict__ total_out, ull* __restrict__ desc, int nb) {
  __shared__ unsigned sc[256];
  __shared__ unsigned s_pref;
  int bid = blockIdx.x;
  int base = bid * 1024 + threadIdx.x * 4;
  unsigned v[4]; unsigned s = 0;
#pragma unroll
  for (int k = 0; k < 4; k++) {
    int i = base + k;
    v[k] = (i < ntot) ? in[i] : 0u;
    s += v[k];
  }
  sc[threadIdx.x] = s;
  __syncthreads();
  unsigned xv = s;
  for (int o = 1; o < 256; o <<= 1) {
    unsigned y = (threadIdx.x >= o) ? sc[threadIdx.x - o] : 0u;
    __syncthreads();
    xv += y;
    sc[threadIdx.x] = xv;
    __syncthreads();
  }
  unsigned btot = sc[255];
  if (threadIdx.x == 0) {
    unsigned ex = 0;
    if (bid == 0) {
      atomicExch(&desc[0], (2ULL << 32) | (ull)btot);
    } else {
      atomicExch(&desc[bid], (1ULL << 32) | (ull)btot);
      int p = bid - 1;
      while (true) {
        ull d = atomicAdd(&desc[p], 0ULL);
        unsigned fl = (unsigned)(d >> 32);
        if (fl == 2u) { ex += (unsigned)d; break; }
        if (fl == 1u) { ex += (unsigned)d; --p; }
      }
      atomicExch(&desc[bid], (2ULL << 32) | (ull)(ex + btot));
    }
    s_pref = ex;
    if (total_out && bid == nb - 1) *total_out = ex + btot;
  }
  __syncthreads();
  unsigned run = s_pref + xv - s;
#pragma unroll
  for (int k = 0; k < 4; k++) {
    int i = base + k;
    if (i < ntot) out[i] = run;
    run += v[k];
  }
}

// map raw->cluster id, count members, pack slot r into cluster: (r<<17)|cl
__global__ void node_cnt_k(const unsigned* __restrict__ rank, int* __restrict__ cluster,
                           unsigned* __restrict__ cnt) {
  int i = blockIdx.x * blockDim.x + threadIdx.x;
  if (i >= NN) return;
  unsigned cl = rank[cluster[i]];
  unsigned r = atomicAdd(&cnt[cl], 1u);
  cluster[i] = (int)((r << 17) | cl);
}

// atomic-free: position = node_off[cl] + packed slot
__global__ void node_scatter_k(const int* __restrict__ cluster,
                               const unsigned* __restrict__ node_off,
                               int* __restrict__ nlist) {
  int i = blockIdx.x * blockDim.x + threadIdx.x;
  if (i >= NN) return;
  unsigned c = (unsigned)cluster[i];
  nlist[node_off[c & 0x1FFFFu] + (c >> 17)] = i;
}

// one wave per cluster: gather member rows, fmax in registers, write once.
__global__ void __launch_bounds__(256)
cluster_reduce_k(const float* __restrict__ x, const float* __restrict__ pos,
                 const int* __restrict__ batch, const int* __restrict__ nlist,
                 const unsigned* __restrict__ node_off, const unsigned* __restrict__ hdr,
                 float* __restrict__ out_x, float* __restrict__ out_pos,
                 float* __restrict__ out_batch) {
  int w = (blockIdx.x * blockDim.x + threadIdx.x) >> 6;
  int nw = (gridDim.x * blockDim.x) >> 6;
  int f = threadIdx.x & 63;
  int ncl = (int)hdr[8];
  for (int c = w; c < ncl; c += nw) {
    unsigned o0 = node_off[c];
    int len = (int)(node_off[c + 1] - o0);
    float mx = -1e38f;
    long long ps = 0;
    for (int m = 0; m < len; m++) {
      int nd = nlist[o0 + m];
      mx = fmaxf(mx, x[(size_t)nd * FF + f]);
      if (f < 3) ps += (long long)llrintf(pos[nd * 3 + f] * 65536.0f);
    }
    out_x[(size_t)c * FF + f] = mx;
    if (f < 3) {
      float v = (float)((double)ps / 65536.0 / (double)len);
      if (f > 0) v = floorf(v / 4.0f);
      out_pos[c * 3 + f] = v;
    }
    if (f == 63) out_batch[c] = (float)batch[nlist[o0]];
  }
}

__global__ void node_tail_k(const unsigned* __restrict__ hdr,
                            float* __restrict__ out_x, float* __restrict__ out_pos,
                            float* __restrict__ out_batch) {
  int ncl = (int)hdr[8];
  int total = (NN - ncl) * FF;
  for (int i = blockIdx.x * blockDim.x + threadIdx.x; i < total;
       i += gridDim.x * blockDim.x) {
    int r = ncl + (i >> 6), f = i & 63;
    out_x[(size_t)r * FF + f] = 0.0f;
    if (f < 3) out_pos[r * 3 + f] = 0.0f;
    if (f == 0) out_batch[r] = -1.0f;
  }
}

// ---- edge pipeline ----

__global__ void __launch_bounds__(256)
coarse_cnt_k(const int* __restrict__ ei, const int* __restrict__ cluster,
             unsigned* __restrict__ mat) {
  __shared__ unsigned h[NBUCK];
  for (int i = threadIdx.x; i < NBUCK; i += 256) h[i] = 0u;
  __syncthreads();
  int t0 = blockIdx.x * TILE;
  for (int k = threadIdx.x; k < TILE; k += 256) {
    int t = t0 + k;
    if (t >= EE) break;
    unsigned s = (unsigned)cluster[ei[t]] & 0x1FFFFu;
    unsigned d = (unsigned)cluster[ei[EE + t]] & 0x1FFFFu;
    if (s != d) atomicAdd(&h[s >> 5], 1u);
  }
  __syncthreads();
  for (int i = threadIdx.x; i < NBUCK; i += 256)
    mat[(size_t)blockIdx.x * NBUCK + i] = h[i];
}

__global__ void transpose_k(const unsigned* __restrict__ mat, unsigned* __restrict__ matT) {
  int f = blockIdx.x * blockDim.x + threadIdx.x;
  if (f >= NSB * NBUCK) return;
  int cb = f / NSB, blk = f - cb * NSB;
  matT[f] = mat[(size_t)blk * NBUCK + cb];
}

// keys[p] = (s_low5 << 39) | (d << 22) | eid ; single-writer contiguous chunks
__global__ void __launch_bounds__(256)
coarse_scatter_k(const int* __restrict__ ei, const int* __restrict__ cluster,
                 const unsigned* __restrict__ matT, ull* __restrict__ keys) {
  __shared__ unsigned cur[NBUCK];
  for (int i = threadIdx.x; i < NBUCK; i += 256)
    cur[i] = matT[(size_t)i * NSB + blockIdx.x];
  __syncthreads();
  int t0 = blockIdx.x * TILE;
  for (int k = threadIdx.x; k < TILE; k += 256) {
    int t = t0 + k;
    if (t >= EE) break;
    unsigned s = (unsigned)cluster[ei[t]] & 0x1FFFFu;
    unsigned d = (unsigned)cluster[ei[EE + t]] & 0x1FFFFu;
    if (s == d) continue;
    unsigned p = atomicAdd(&cur[s >> 5], 1u);
    keys[p] = ((ull)(s & 31u) << 39) | ((ull)d << 22) | (unsigned)t;
  }
}

// FUSED grouping+emit (r14 structure: per-element flat loops = max TLP).
// Hot-loop work reduced: one fused b32 scan computes head + rank (singleton
// case) together; keys split into cd17[] (scanned) and eidj[] (emit only).
__global__ void __launch_bounds__(256)
grp_emit_k(const ull* __restrict__ keys, const unsigned* __restrict__ matT,
           unsigned* __restrict__ hdr, ull* __restrict__ desc,
           const float* __restrict__ ea,
           float* __restrict__ out_src, float* __restrict__ out_dst,
           float* __restrict__ out_ea) {
  __shared__ unsigned cd17[CAP];                 // d (17b), the scan key
  __shared__ unsigned eidj[CAP];                 // eid (22b) | j<<22
  __shared__ unsigned short hr[CAP];             // rank | 0x8000 if head
  __shared__ unsigned h[SUBB], pre[SUBB + 1], cur[SUBB], hc[SUBB], hpre[SUBB];
  __shared__ unsigned sG, sBase, sCnt, sBid;
  int tid = threadIdx.x;
  // ticket: monotone bucket acquisition -> lookback progress guaranteed
  if (tid == 0) sBid = atomicAdd(&hdr[13], 1u);
  __syncthreads();
  int cb = (int)sBid;
  unsigned start = matT[(size_t)cb * NSB];
  unsigned end = (cb == NBUCK - 1) ? hdr[11] : matT[(size_t)(cb + 1) * NSB];
  int len = (int)(end - start);
  bool lds = (len <= CAP);
  unsigned G = 0;

  if (len > 0 && lds) {
    if (tid < SUBB) { h[tid] = 0u; hc[tid] = 0u; }
    __syncthreads();
    for (int i = tid; i < len; i += 256)
      atomicAdd(&h[(unsigned)(keys[start + i] >> 39) & (SUBB - 1u)], 1u);
    __syncthreads();
    if (tid == 0) {
      unsigned run = 0;
      for (int j = 0; j < SUBB; j++) { pre[j] = run; run += h[j]; }
      pre[SUBB] = run;
    }
    __syncthreads();
    if (tid < SUBB) cur[tid] = pre[tid];
    __syncthreads();
    for (int i = tid; i < len; i += 256) {
      ull v = keys[start + i];                 // L2-hot second read
      unsigned j = (unsigned)(v >> 39) & (SUBB - 1u);
      unsigned p = atomicAdd(&cur[j], 1u);
      cd17[p] = (unsigned)((v >> 22) & 0x1FFFFULL);
      eidj[p] = (unsigned)(v & 0x3FFFFFULL) | (j << 22);
    }
    __syncthreads();
    // fused pass: head + cntSmaller in ONE b32 scan per element
    for (int i = tid; i < len; i += 256) {
      unsigned j = eidj[i] >> 22;
      unsigned mine = cd17[i];
      int lo = (int)pre[j], hi = (int)pre[j + 1];
      unsigned cntSm = 0, eqB = 0;
      for (int q = lo; q < hi; ++q) {
        unsigned c = cd17[q];
        cntSm += (c < mine) ? 1u : 0u;
        eqB += (c == mine && q < i) ? 1u : 0u;
      }
      bool head = (eqB == 0u);
      hr[i] = (unsigned short)(cntSm | (head ? 0x8000u : 0u));
      if (head) atomicAdd(&hc[j], 1u);
    }
    __syncthreads();
    // rare fixup: non-singleton sub-buckets need rank among DISTINCT cds
    for (int i = tid; i < len; i += 256) {
      unsigned j = eidj[i] >> 22;
      if (hc[j] == pre[j + 1] - pre[j]) continue;       // all distinct
      if (!(hr[i] & 0x8000u)) continue;
      unsigned mine = cd17[i];
      unsigned r = 0;
      for (int q = (int)pre[j]; q < (int)pre[j + 1]; ++q)
        r += ((hr[q] & 0x8000u) && cd17[q] < mine) ? 1u : 0u;
      hr[i] = (unsigned short)(0x8000u | r);
    }
    __syncthreads();
    if (tid == 0) {
      unsigned run = 0;
      for (int j = 0; j < SUBB; j++) { hpre[j] = run; run += hc[j]; }
      sG = run;
    }
    __syncthreads();
    G = sG;
  } else if (len > 0) {
    // insurance (len > CAP, unreachable for this data): per-sub-bucket staging
    if (tid == 0) sG = 0;
    __syncthreads();
    for (int j = 0; j < SUBB; j++) {
      if (tid == 0) sCnt = 0;
      __syncthreads();
      for (int i = tid; i < len; i += 256) {
        ull v = keys[start + i];
        if (((unsigned)(v >> 39) & (SUBB - 1u)) == (unsigned)j) {
          unsigned p = atomicAdd(&sCnt, 1u);
          if (p < CAP) {
            cd17[p] = (unsigned)((v >> 22) & 0x1FFFFULL);
            eidj[p] = (unsigned)(v & 0x3FFFFFULL);
          }
        }
      }
      __syncthreads();
      int sl = min((int)sCnt, CAP);
      for (int i = tid; i < sl; i += 256) {
        unsigned mine = cd17[i];
        bool head = true;
        for (int q = 0; q < i; ++q)
          head = head && (cd17[q] != mine);
        hr[i] = head ? 0x8000u : 0u;
      }
      __syncthreads();
      if (tid == 0) {
        unsigned c = 0;
        for (int q = 0; q < sl; ++q) c += (hr[q] & 0x8000u) ? 1u : 0u;
        hc[j] = c; hpre[j] = sG; sG += c;
      }
      __syncthreads();
    }
    G = sG;
  }

  // inline decoupled lookback over coarse buckets -> global row base
  if (tid == 0) {
    unsigned ex = 0;
    if (cb == 0) {
      atomicExch(&desc[0], (2ULL << 32) | (ull)G);
    } else {
      atomicExch(&desc[cb], (1ULL << 32) | (ull)G);
      int p = cb - 1;
      while (true) {
        ull d = atomicAdd(&desc[p], 0ULL);
        unsigned fl = (unsigned)(d >> 32);
        if (fl == 2u) { ex += (unsigned)d; break; }
        if (fl == 1u) { ex += (unsigned)d; --p; }
      }
      atomicExch(&desc[cb], (2ULL << 32) | (ull)(ex + G));
    }
    sBase = ex;
    if (cb == NBUCK - 1) hdr[12] = ex + G;   // total groups for tail_fill
  }
  __syncthreads();
  unsigned base = sBase;
  if (len <= 0) return;

  if (lds) {
    // flat emit: max gather concurrency, rank from hr lookup
    for (int i = tid; i < len; i += 256) {
      unsigned hrv = hr[i];
      if (!(hrv & 0x8000u)) continue;
      unsigned ej = eidj[i];
      unsigned j = ej >> 22;
      unsigned mine = cd17[i];
      const float4* p4 = (const float4*)&ea[(size_t)(ej & 0x3FFFFFu) * FEA];
      float4 a0 = p4[0], a1 = p4[1];
      if (hc[j] != pre[j + 1] - pre[j]) {        // non-singleton sub-bucket
        for (unsigned q = pre[j]; q < pre[j + 1]; ++q) {
          if (q == (unsigned)i) continue;
          if (cd17[q] == mine) {
            const float4* q4 = (const float4*)&ea[(size_t)(eidj[q] & 0x3FFFFFu) * FEA];
            float4 b0 = q4[0], b1 = q4[1];
            a0.x += b0.x; a0.y += b0.y; a0.z += b0.z; a0.w += b0.w;
            a1.x += b1.x; a1.y += b1.y; a1.z += b1.z; a1.w += b1.w;
          }
        }
      }
      unsigned row = base + hpre[j] + (hrv & 0x7FFFu);
      out_src[row] = (float)(cb * SUBB + (int)j);
      out_dst[row] = (float)mine;
      float4* o = (float4*)&out_ea[(size_t)row * FEA];
      o[0] = a0; o[1] = a1;
    }
  } else {
    // insurance emit: redo per-sub-bucket staging and emit
    for (int j = 0; j < SUBB; j++) {
      if (tid == 0) sCnt = 0;
      __syncthreads();
      for (int i = tid; i < len; i += 256) {
        ull v = keys[start + i];
        if (((unsigned)(v >> 39) & (SUBB - 1u)) == (unsigned)j) {
          unsigned p = atomicAdd(&sCnt, 1u);
          if (p < CAP) {
            cd17[p] = (unsigned)((v >> 22) & 0x1FFFFULL);
            eidj[p] = (unsigned)(v & 0x3FFFFFULL);
          }
        }
      }
      __syncthreads();
      int sl = min((int)sCnt, CAP);
      for (int i = tid; i < sl; i += 256) {
        unsigned mine = cd17[i];
        bool head = true;
        for (int q = 0; q < i; ++q)
          head = head && (cd17[q] != mine);
        hr[i] = head ? 0x8000u : 0u;
      }
      __syncthreads();
      for (int i = tid; i < sl; i += 256) {
        if (!(hr[i] & 0x8000u)) continue;
        unsigned mine = cd17[i];
        unsigned r = 0;
        for (int q = 0; q < sl; ++q)
          r += ((hr[q] & 0x8000u) && cd17[q] < mine) ? 1u : 0u;
        const float4* p4 = (const float4*)&ea[(size_t)(eidj[i] & 0x3FFFFFu) * FEA];
        float4 a0 = p4[0], a1 = p4[1];
        if (hc[j] != (unsigned)sl) {
          for (int q = 0; q < sl; ++q) {
            if (q == i) continue;
            if (cd17[q] == mine) {
              const float4* q4 = (const float4*)&ea[(size_t)(eidj[q] & 0x3FFFFFu) * FEA];
              float4 b0 = q4[0], b1 = q4[1];
              a0.x += b0.x; a0.y += b0.y; a0.z += b0.z; a0.w += b0.w;
              a1.x += b1.x; a1.y += b1.y; a1.z += b1.z; a1.w += b1.w;
            }
          }
        }
        unsigned row = base + hpre[j] + r;
        out_src[row] = (float)(cb * SUBB + j);
        out_dst[row] = (float)mine;
        float4* o = (float4*)&out_ea[(size_t)row * FEA];
        o[0] = a0; o[1] = a1;
      }
      __syncthreads();
    }
  }
}

// rows >= T get -1/-1 and zero ea (T = hdr[12] from grp_emit)
__global__ void tail_fill_k(const unsigned* __restrict__ hdr,
                            float* __restrict__ out_src, float* __restrict__ out_dst,
                            float* __restrict__ out_ea) {
  int T = (int)hdr[12];
  for (int t = T + blockIdx.x * blockDim.x + threadIdx.x; t < EE;
       t += gridDim.x * blockDim.x) {
    out_src[t] = -1.0f;
    out_dst[t] = -1.0f;
    float4 z = make_float4(0.f, 0.f, 0.f, 0.f);
    float4* o = (float4*)&out_ea[(size_t)t * FEA];
    o[0] = z; o[1] = z;
  }
}

extern "C" void kernel_launch(void* const* d_in, const int* in_sizes, int n_in,
                              void* d_out, int out_size, void* d_ws, size_t ws_size,
                              hipStream_t stream) {
  const float* x   = (const float*)d_in[0];
  const float* pos = (const float*)d_in[1];
  const int* batch = (const int*)d_in[2];
  const int* ei    = (const int*)d_in[3];
  const float* ea  = (const float*)d_in[4];
  float* out = (float*)d_out;

  const size_t OX = 0;
  const size_t OP = (size_t)NN * FF;
  const size_t OB = OP + (size_t)NN * 3;
  const size_t OE = OB + (size_t)NN;
  const size_t OA = OE + (size_t)2 * EE;

  char* w = (char*)d_ws;
  size_t woff = 0;
  auto alloc = [&](size_t bytes) -> void* {
    void* p = w + woff;
    woff += (bytes + 255) & ~(size_t)255;
    return p;
  };
  // zeroed region (one memset)
  unsigned* rank    = (unsigned*)alloc((size_t)RAWCAP * 4);
  unsigned* cnt     = (unsigned*)alloc((size_t)(NN + 1) * 4);
  ull* desc0        = (ull*)alloc(4096 * 8);
  ull* desc1        = (ull*)alloc(4096 * 8);
  ull* desc2        = (ull*)alloc(4096 * 8);
  ull* desc3        = (ull*)alloc(4096 * 8);
  size_t zero_bytes = woff;
  // written-before-read region
  int* cluster      = (int*)alloc((size_t)NN * 4);
  int* nlist        = (int*)alloc((size_t)NN * 4);
  unsigned* node_off= (unsigned*)alloc((size_t)(NN + 2) * 4);
  unsigned* mat     = (unsigned*)alloc((size_t)NSB * NBUCK * 4);
  unsigned* matT    = (unsigned*)alloc((size_t)NSB * NBUCK * 4);
  unsigned* hdr     = (unsigned*)alloc(256);
  ull* keys         = (ull*)alloc((size_t)EE * 8);

  hipMemsetAsync(d_ws, 0, zero_bytes, stream);

  init_hdr_k<<<1, 64, 0, stream>>>(hdr);
  minmax_k<<<128, 256, 0, stream>>>(pos, hdr);
  dims_k<<<1, 64, 0, stream>>>(hdr);
  raw_k<<<(NN + 255) / 256, 256, 0, stream>>>(pos, batch, hdr, cluster, rank);

  auto scan1 = [&](const unsigned* in_, unsigned* out_, int ntot,
                   unsigned* total_out, ull* d_) {
    int nb = (ntot + 1023) / 1024;
    scan_lb_k<<<nb, 256, 0, stream>>>(in_, out_, ntot, total_out, d_, nb);
  };
  scan1(rank, rank, RAWCAP, hdr + 8, desc0);   // rank[raw]=cluster id; total->ncl

  node_cnt_k<<<(NN + 255) / 256, 256, 0, stream>>>(rank, cluster, cnt);
  scan1(cnt, node_off, NN + 1, nullptr, desc1);
  node_scatter_k<<<(NN + 255) / 256, 256, 0, stream>>>(cluster, node_off, nlist);
  cluster_reduce_k<<<2048, 256, 0, stream>>>(x, pos, batch, nlist, node_off, hdr,
                                             out + OX, out + OP, out + OB);
  node_tail_k<<<2048, 256, 0, stream>>>(hdr, out + OX, out + OP, out + OB);

  coarse_cnt_k<<<NSB, 256, 0, stream>>>(ei, cluster, mat);
  transpose_k<<<(NSB * NBUCK + 255) / 256, 256, 0, stream>>>(mat, matT);
  scan1(matT, matT, NSB * NBUCK, hdr + 11, desc2);   // chunk offsets; total->Etot
  coarse_scatter_k<<<NSB, 256, 0, stream>>>(ei, cluster, matT, keys);
  grp_emit_k<<<NBUCK, 256, 0, stream>>>(keys, matT, hdr, desc3, ea,
                                        out + OE, out + OE + EE, out + OA);
  tail_fill_k<<<512, 256, 0, stream>>>(hdr, out + OE, out + OE + EE, out + OA);
}

// Round 20
// 402.785 us; speedup vs baseline: 1.1456x; 1.0516x over previous
//
#include <hip/hip_runtime.h>

#define NN 300000
#define FF 64
#define EE 2400000
#define FEA 8
#define RAWCAP 131072   // >= 8*129*97 = 100104 (so cluster ids < 2^17)
#define NBUCK 4096      // coarse buckets: cb = cs>>5
#define SUBB 32         // sub-buckets (cs ids) per coarse bucket
#define NSB 256         // scatter blocks (512 threads each): halves chunk fragmentation
#define TILE ((EE + NSB - 1) / NSB)
#define CAP 2048        // LDS capacity per coarse bucket (mean ~586, 3.5x margin)

typedef unsigned long long ull;

__device__ __forceinline__ unsigned fenc(float f) {
  unsigned b = __float_as_uint(f);
  return (b & 0x80000000u) ? ~b : (b | 0x80000000u);
}
__device__ __forceinline__ float fdec(unsigned e) {
  unsigned b = (e & 0x80000000u) ? (e ^ 0x80000000u) : ~e;
  return __uint_as_float(b);
}

__global__ void init_hdr_k(unsigned* hdr) {
  if (threadIdx.x == 0) {
    hdr[0] = 0xFFFFFFFFu; hdr[1] = 0xFFFFFFFFu;  // min enc
    hdr[2] = 0u;          hdr[3] = 0u;           // max enc
    hdr[13] = 0u;                                 // grp_emit ticket
  }
}

__global__ void minmax_k(const float* __restrict__ pos, unsigned* hdr) {
  __shared__ unsigned red[4][4];
  int t = blockIdx.x * blockDim.x + threadIdx.x;
  float mnx = 1e30f, mny = 1e30f, mxx = -1e30f, mxy = -1e30f;
  for (int i = t; i < NN; i += gridDim.x * blockDim.x) {
    float px = pos[i * 3 + 1], py = pos[i * 3 + 2];
    mnx = fminf(mnx, px); mny = fminf(mny, py);
    mxx = fmaxf(mxx, px); mxy = fmaxf(mxy, py);
  }
  for (int o = 1; o < 64; o <<= 1) {
    mnx = fminf(mnx, __shfl_xor(mnx, o));
    mny = fminf(mny, __shfl_xor(mny, o));
    mxx = fmaxf(mxx, __shfl_xor(mxx, o));
    mxy = fmaxf(mxy, __shfl_xor(mxy, o));
  }
  int wid = threadIdx.x >> 6;
  if ((threadIdx.x & 63) == 0) {
    red[wid][0] = fenc(mnx); red[wid][1] = fenc(mny);
    red[wid][2] = fenc(mxx); red[wid][3] = fenc(mxy);
  }
  __syncthreads();
  if (threadIdx.x == 0) {
    unsigned a0 = red[0][0], a1 = red[0][1], a2 = red[0][2], a3 = red[0][3];
    for (int k = 1; k < 4; k++) {
      a0 = min(a0, red[k][0]); a1 = min(a1, red[k][1]);
      a2 = max(a2, red[k][2]); a3 = max(a3, red[k][3]);
    }
    atomicMin(&hdr[0], a0); atomicMin(&hdr[1], a1);
    atomicMax(&hdr[2], a2); atomicMax(&hdr[3], a3);
  }
}

__global__ void dims_k(unsigned* hdr) {
  if (threadIdx.x == 0 && blockIdx.x == 0) {
    float mnx = fdec(hdr[0]), mny = fdec(hdr[1]);
    float mxx = fdec(hdr[2]), mxy = fdec(hdr[3]);
    int d0 = (int)(floorf((mxx - mnx) / 5.0f) + 1.0f);
    int d1 = (int)(floorf((mxy - mny) / 5.0f) + 1.0f);
    hdr[4] = (unsigned)d0;
    hdr[5] = (unsigned)d1;
    ((float*)hdr)[6] = mnx;
    ((float*)hdr)[7] = mny;
  }
}

__global__ void raw_k(const float* __restrict__ pos, const int* __restrict__ batch,
                      const unsigned* __restrict__ hdr, int* __restrict__ cluster,
                      unsigned* __restrict__ flags) {
  int i = blockIdx.x * blockDim.x + threadIdx.x;
  if (i >= NN) return;
  float mnx = ((const float*)hdr)[6], mny = ((const float*)hdr)[7];
  int d0 = (int)hdr[4], d1 = (int)hdr[5];
  int c0 = (int)floorf((pos[i * 3 + 1] - mnx) / 5.0f);
  int c1 = (int)floorf((pos[i * 3 + 2] - mny) / 5.0f);
  int raw = batch[i] * (d0 * d1) + c0 * d1 + c1;
  cluster[i] = raw;
  flags[raw] = 1u;
}

// single-kernel exclusive scan: decoupled lookback (validated r8-r19)
__global__ void __launch_bounds__(256)
scan_lb_k(const unsigned* __restrict__ in, unsigned* __restrict__ out, int ntot,
          unsigned* __restrict__ total_out, ull* __restrict__ desc, int nb) {
  __shared__ unsigned sc[256];
  __shared__ unsigned s_pref;
  int bid = blockIdx.x;
  int base = bid * 1024 + threadIdx.x * 4;
  unsigned v[4]; unsigned s = 0;
#pragma unroll
  for (int k = 0; k < 4; k++) {
    int i = base + k;
    v[k] = (i < ntot) ? in[i] : 0u;
    s += v[k];
  }
  sc[threadIdx.x] = s;
  __syncthreads();
  unsigned xv = s;
  for (int o = 1; o < 256; o <<= 1) {
    unsigned y = (threadIdx.x >= o) ? sc[threadIdx.x - o] : 0u;
    __syncthreads();
    xv += y;
    sc[threadIdx.x] = xv;
    __syncthreads();
  }
  unsigned btot = sc[255];
  if (threadIdx.x == 0) {
    unsigned ex = 0;
    if (bid == 0) {
      atomicExch(&desc[0], (2ULL << 32) | (ull)btot);
    } else {
      atomicExch(&desc[bid], (1ULL << 32) | (ull)btot);
      int p = bid - 1;
      while (true) {
        ull d = atomicAdd(&desc[p], 0ULL);
        unsigned fl = (unsigned)(d >> 32);
        if (fl == 2u) { ex += (unsigned)d; break; }
        if (fl == 1u) { ex += (unsigned)d; --p; }
      }
      atomicExch(&desc[bid], (2ULL << 32) | (ull)(ex + btot));
    }
    s_pref = ex;
    if (total_out && bid == nb - 1) *total_out = ex + btot;
  }
  __syncthreads();
  unsigned run = s_pref + xv - s;
#pragma unroll
  for (int k = 0; k < 4; k++) {
    int i = base + k;
    if (i < ntot) out[i] = run;
    run += v[k];
  }
}

// map raw->cluster id, count members, pack slot r into cluster: (r<<17)|cl
__global__ void node_cnt_k(const unsigned* __restrict__ rank, int* __restrict__ cluster,
                           unsigned* __restrict__ cnt) {
  int i = blockIdx.x * blockDim.x + threadIdx.x;
  if (i >= NN) return;
  unsigned cl = rank[cluster[i]];
  unsigned r = atomicAdd(&cnt[cl], 1u);
  cluster[i] = (int)((r << 17) | cl);
}

// atomic-free: position = node_off[cl] + packed slot
__global__ void node_scatter_k(const int* __restrict__ cluster,
                               const unsigned* __restrict__ node_off,
                               int* __restrict__ nlist) {
  int i = blockIdx.x * blockDim.x + threadIdx.x;
  if (i >= NN) return;
  unsigned c = (unsigned)cluster[i];
  nlist[node_off[c & 0x1FFFFu] + (c >> 17)] = i;
}

// one wave per cluster: gather member rows, fmax in registers, write once.
__global__ void __launch_bounds__(256)
cluster_reduce_k(const float* __restrict__ x, const float* __restrict__ pos,
                 const int* __restrict__ batch, const int* __restrict__ nlist,
                 const unsigned* __restrict__ node_off, const unsigned* __restrict__ hdr,
                 float* __restrict__ out_x, float* __restrict__ out_pos,
                 float* __restrict__ out_batch) {
  int w = (blockIdx.x * blockDim.x + threadIdx.x) >> 6;
  int nw = (gridDim.x * blockDim.x) >> 6;
  int f = threadIdx.x & 63;
  int ncl = (int)hdr[8];
  for (int c = w; c < ncl; c += nw) {
    unsigned o0 = node_off[c];
    int len = (int)(node_off[c + 1] - o0);
    float mx = -1e38f;
    long long ps = 0;
    for (int m = 0; m < len; m++) {
      int nd = nlist[o0 + m];
      mx = fmaxf(mx, x[(size_t)nd * FF + f]);
      if (f < 3) ps += (long long)llrintf(pos[nd * 3 + f] * 65536.0f);
    }
    out_x[(size_t)c * FF + f] = mx;
    if (f < 3) {
      float v = (float)((double)ps / 65536.0 / (double)len);
      if (f > 0) v = floorf(v / 4.0f);
      out_pos[c * 3 + f] = v;
    }
    if (f == 63) out_batch[c] = (float)batch[nlist[o0]];
  }
}

__global__ void node_tail_k(const unsigned* __restrict__ hdr,
                            float* __restrict__ out_x, float* __restrict__ out_pos,
                            float* __restrict__ out_batch) {
  int ncl = (int)hdr[8];
  int total = (NN - ncl) * FF;
  for (int i = blockIdx.x * blockDim.x + threadIdx.x; i < total;
       i += gridDim.x * blockDim.x) {
    int r = ncl + (i >> 6), f = i & 63;
    out_x[(size_t)r * FF + f] = 0.0f;
    if (f < 3) out_pos[r * 3 + f] = 0.0f;
    if (f == 0) out_batch[r] = -1.0f;
  }
}

// ---- edge pipeline ----

__global__ void __launch_bounds__(512)
coarse_cnt_k(const int* __restrict__ ei, const int* __restrict__ cluster,
             unsigned* __restrict__ mat) {
  __shared__ unsigned h[NBUCK];
  for (int i = threadIdx.x; i < NBUCK; i += 512) h[i] = 0u;
  __syncthreads();
  int t0 = blockIdx.x * TILE;
  for (int k = threadIdx.x; k < TILE; k += 512) {
    int t = t0 + k;
    if (t >= EE) break;
    unsigned s = (unsigned)cluster[ei[t]] & 0x1FFFFu;
    unsigned d = (unsigned)cluster[ei[EE + t]] & 0x1FFFFu;
    if (s != d) atomicAdd(&h[s >> 5], 1u);
  }
  __syncthreads();
  for (int i = threadIdx.x; i < NBUCK; i += 512)
    mat[(size_t)blockIdx.x * NBUCK + i] = h[i];
}

__global__ void transpose_k(const unsigned* __restrict__ mat, unsigned* __restrict__ matT) {
  int f = blockIdx.x * blockDim.x + threadIdx.x;
  if (f >= NSB * NBUCK) return;
  int cb = f / NSB, blk = f - cb * NSB;
  matT[f] = mat[(size_t)blk * NBUCK + cb];
}

// keys[p] = (s_low5 << 39) | (d << 22) | eid ; single-writer contiguous chunks
__global__ void __launch_bounds__(512)
coarse_scatter_k(const int* __restrict__ ei, const int* __restrict__ cluster,
                 const unsigned* __restrict__ matT, ull* __restrict__ keys) {
  __shared__ unsigned cur[NBUCK];
  for (int i = threadIdx.x; i < NBUCK; i += 512)
    cur[i] = matT[(size_t)i * NSB + blockIdx.x];
  __syncthreads();
  int t0 = blockIdx.x * TILE;
  for (int k = threadIdx.x; k < TILE; k += 512) {
    int t = t0 + k;
    if (t >= EE) break;
    unsigned s = (unsigned)cluster[ei[t]] & 0x1FFFFu;
    unsigned d = (unsigned)cluster[ei[EE + t]] & 0x1FFFFu;
    if (s == d) continue;
    unsigned p = atomicAdd(&cur[s >> 5], 1u);
    keys[p] = ((ull)(s & 31u) << 39) | ((ull)d << 22) | (unsigned)t;
  }
}

// FUSED grouping+emit (r14 structure: per-element flat loops = max TLP).
// Hot-loop work reduced: one fused b32 scan computes head + rank (singleton
// case) together; keys split into cd17[] (scanned) and eidj[] (emit only).
__global__ void __launch_bounds__(256)
grp_emit_k(const ull* __restrict__ keys, const unsigned* __restrict__ matT,
           unsigned* __restrict__ hdr, ull* __restrict__ desc,
           const float* __restrict__ ea,
           float* __restrict__ out_src, float* __restrict__ out_dst,
           float* __restrict__ out_ea) {
  __shared__ unsigned cd17[CAP];                 // d (17b), the scan key
  __shared__ unsigned eidj[CAP];                 // eid (22b) | j<<22
  __shared__ unsigned short hr[CAP];             // rank | 0x8000 if head
  __shared__ unsigned h[SUBB], pre[SUBB + 1], cur[SUBB], hc[SUBB], hpre[SUBB];
  __shared__ unsigned sG, sBase, sCnt, sBid;
  int tid = threadIdx.x;
  // ticket: monotone bucket acquisition -> lookback progress guaranteed
  if (tid == 0) sBid = atomicAdd(&hdr[13], 1u);
  __syncthreads();
  int cb = (int)sBid;
  unsigned start = matT[(size_t)cb * NSB];
  unsigned end = (cb == NBUCK - 1) ? hdr[11] : matT[(size_t)(cb + 1) * NSB];
  int len = (int)(end - start);
  bool lds = (len <= CAP);
  unsigned G = 0;

  if (len > 0 && lds) {
    if (tid < SUBB) { h[tid] = 0u; hc[tid] = 0u; }
    __syncthreads();
    for (int i = tid; i < len; i += 256)
      atomicAdd(&h[(unsigned)(keys[start + i] >> 39) & (SUBB - 1u)], 1u);
    __syncthreads();
    if (tid == 0) {
      unsigned run = 0;
      for (int j = 0; j < SUBB; j++) { pre[j] = run; run += h[j]; }
      pre[SUBB] = run;
    }
    __syncthreads();
    if (tid < SUBB) cur[tid] = pre[tid];
    __syncthreads();
    for (int i = tid; i < len; i += 256) {
      ull v = keys[start + i];                 // L2-hot second read
      unsigned j = (unsigned)(v >> 39) & (SUBB - 1u);
      unsigned p = atomicAdd(&cur[j], 1u);
      cd17[p] = (unsigned)((v >> 22) & 0x1FFFFULL);
      eidj[p] = (unsigned)(v & 0x3FFFFFULL) | (j << 22);
    }
    __syncthreads();
    // fused pass: head + cntSmaller in ONE b32 scan per element
    for (int i = tid; i < len; i += 256) {
      unsigned j = eidj[i] >> 22;
      unsigned mine = cd17[i];
      int lo = (int)pre[j], hi = (int)pre[j + 1];
      unsigned cntSm = 0, eqB = 0;
      for (int q = lo; q < hi; ++q) {
        unsigned c = cd17[q];
        cntSm += (c < mine) ? 1u : 0u;
        eqB += (c == mine && q < i) ? 1u : 0u;
      }
      bool head = (eqB == 0u);
      hr[i] = (unsigned short)(cntSm | (head ? 0x8000u : 0u));
      if (head) atomicAdd(&hc[j], 1u);
    }
    __syncthreads();
    // rare fixup: non-singleton sub-buckets need rank among DISTINCT cds
    for (int i = tid; i < len; i += 256) {
      unsigned j = eidj[i] >> 22;
      if (hc[j] == pre[j + 1] - pre[j]) continue;       // all distinct
      if (!(hr[i] & 0x8000u)) continue;
      unsigned mine = cd17[i];
      unsigned r = 0;
      for (int q = (int)pre[j]; q < (int)pre[j + 1]; ++q)
        r += ((hr[q] & 0x8000u) && cd17[q] < mine) ? 1u : 0u;
      hr[i] = (unsigned short)(0x8000u | r);
    }
    __syncthreads();
    if (tid == 0) {
      unsigned run = 0;
      for (int j = 0; j < SUBB; j++) { hpre[j] = run; run += hc[j]; }
      sG = run;
    }
    __syncthreads();
    G = sG;
  } else if (len > 0) {
    // insurance (len > CAP, unreachable for this data): per-sub-bucket staging
    if (tid == 0) sG = 0;
    __syncthreads();
    for (int j = 0; j < SUBB; j++) {
      if (tid == 0) sCnt = 0;
      __syncthreads();
      for (int i = tid; i < len; i += 256) {
        ull v = keys[start + i];
        if (((unsigned)(v >> 39) & (SUBB - 1u)) == (unsigned)j) {
          unsigned p = atomicAdd(&sCnt, 1u);
          if (p < CAP) {
            cd17[p] = (unsigned)((v >> 22) & 0x1FFFFULL);
            eidj[p] = (unsigned)(v & 0x3FFFFFULL);
          }
        }
      }
      __syncthreads();
      int sl = min((int)sCnt, CAP);
      for (int i = tid; i < sl; i += 256) {
        unsigned mine = cd17[i];
        bool head = true;
        for (int q = 0; q < i; ++q)
          head = head && (cd17[q] != mine);
        hr[i] = head ? 0x8000u : 0u;
      }
      __syncthreads();
      if (tid == 0) {
        unsigned c = 0;
        for (int q = 0; q < sl; ++q) c += (hr[q] & 0x8000u) ? 1u : 0u;
        hc[j] = c; hpre[j] = sG; sG += c;
      }
      __syncthreads();
    }
    G = sG;
  }

  // inline decoupled lookback over coarse buckets -> global row base
  if (tid == 0) {
    unsigned ex = 0;
    if (cb == 0) {
      atomicExch(&desc[0], (2ULL << 32) | (ull)G);
    } else {
      atomicExch(&desc[cb], (1ULL << 32) | (ull)G);
      int p = cb - 1;
      while (true) {
        ull d = atomicAdd(&desc[p], 0ULL);
        unsigned fl = (unsigned)(d >> 32);
        if (fl == 2u) { ex += (unsigned)d; break; }
        if (fl == 1u) { ex += (unsigned)d; --p; }
      }
      atomicExch(&desc[cb], (2ULL << 32) | (ull)(ex + G));
    }
    sBase = ex;
    if (cb == NBUCK - 1) hdr[12] = ex + G;   // total groups for tail_fill
  }
  __syncthreads();
  unsigned base = sBase;
  if (len <= 0) return;

  if (lds) {
    // flat emit: max gather concurrency, rank from hr lookup
    for (int i = tid; i < len; i += 256) {
      unsigned hrv = hr[i];
      if (!(hrv & 0x8000u)) continue;
      unsigned ej = eidj[i];
      unsigned j = ej >> 22;
      unsigned mine = cd17[i];
      const float4* p4 = (const float4*)&ea[(size_t)(ej & 0x3FFFFFu) * FEA];
      float4 a0 = p4[0], a1 = p4[1];
      if (hc[j] != pre[j + 1] - pre[j]) {        // non-singleton sub-bucket
        for (unsigned q = pre[j]; q < pre[j + 1]; ++q) {
          if (q == (unsigned)i) continue;
          if (cd17[q] == mine) {
            const float4* q4 = (const float4*)&ea[(size_t)(eidj[q] & 0x3FFFFFu) * FEA];
            float4 b0 = q4[0], b1 = q4[1];
            a0.x += b0.x; a0.y += b0.y; a0.z += b0.z; a0.w += b0.w;
            a1.x += b1.x; a1.y += b1.y; a1.z += b1.z; a1.w += b1.w;
          }
        }
      }
      unsigned row = base + hpre[j] + (hrv & 0x7FFFu);
      out_src[row] = (float)(cb * SUBB + (int)j);
      out_dst[row] = (float)mine;
      float4* o = (float4*)&out_ea[(size_t)row * FEA];
      o[0] = a0; o[1] = a1;
    }
  } else {
    // insurance emit: redo per-sub-bucket staging and emit
    for (int j = 0; j < SUBB; j++) {
      if (tid == 0) sCnt = 0;
      __syncthreads();
      for (int i = tid; i < len; i += 256) {
        ull v = keys[start + i];
        if (((unsigned)(v >> 39) & (SUBB - 1u)) == (unsigned)j) {
          unsigned p = atomicAdd(&sCnt, 1u);
          if (p < CAP) {
            cd17[p] = (unsigned)((v >> 22) & 0x1FFFFULL);
            eidj[p] = (unsigned)(v & 0x3FFFFFULL);
          }
        }
      }
      __syncthreads();
      int sl = min((int)sCnt, CAP);
      for (int i = tid; i < sl; i += 256) {
        unsigned mine = cd17[i];
        bool head = true;
        for (int q = 0; q < i; ++q)
          head = head && (cd17[q] != mine);
        hr[i] = head ? 0x8000u : 0u;
      }
      __syncthreads();
      for (int i = tid; i < sl; i += 256) {
        if (!(hr[i] & 0x8000u)) continue;
        unsigned mine = cd17[i];
        unsigned r = 0;
        for (int q = 0; q < sl; ++q)
          r += ((hr[q] & 0x8000u) && cd17[q] < mine) ? 1u : 0u;
        const float4* p4 = (const float4*)&ea[(size_t)(eidj[i] & 0x3FFFFFu) * FEA];
        float4 a0 = p4[0], a1 = p4[1];
        if (hc[j] != (unsigned)sl) {
          for (int q = 0; q < sl; ++q) {
            if (q == i) continue;
            if (cd17[q] == mine) {
              const float4* q4 = (const float4*)&ea[(size_t)(eidj[q] & 0x3FFFFFu) * FEA];
              float4 b0 = q4[0], b1 = q4[1];
              a0.x += b0.x; a0.y += b0.y; a0.z += b0.z; a0.w += b0.w;
              a1.x += b1.x; a1.y += b1.y; a1.z += b1.z; a1.w += b1.w;
            }
          }
        }
        unsigned row = base + hpre[j] + r;
        out_src[row] = (float)(cb * SUBB + j);
        out_dst[row] = (float)mine;
        float4* o = (float4*)&out_ea[(size_t)row * FEA];
        o[0] = a0; o[1] = a1;
      }
      __syncthreads();
    }
  }
}

// rows >= T get -1/-1 and zero ea (T = hdr[12] from grp_emit)
__global__ void tail_fill_k(const unsigned* __restrict__ hdr,
                            float* __restrict__ out_src, float* __restrict__ out_dst,
                            float* __restrict__ out_ea) {
  int T = (int)hdr[12];
  for (int t = T + blockIdx.x * blockDim.x + threadIdx.x; t < EE;
       t += gridDim.x * blockDim.x) {
    out_src[t] = -1.0f;
    out_dst[t] = -1.0f;
    float4 z = make_float4(0.f, 0.f, 0.f, 0.f);
    float4* o = (float4*)&out_ea[(size_t)t * FEA];
    o[0] = z; o[1] = z;
  }
}

extern "C" void kernel_launch(void* const* d_in, const int* in_sizes, int n_in,
                              void* d_out, int out_size, void* d_ws, size_t ws_size,
                              hipStream_t stream) {
  const float* x   = (const float*)d_in[0];
  const float* pos = (const float*)d_in[1];
  const int* batch = (const int*)d_in[2];
  const int* ei    = (const int*)d_in[3];
  const float* ea  = (const float*)d_in[4];
  float* out = (float*)d_out;

  const size_t OX = 0;
  const size_t OP = (size_t)NN * FF;
  const size_t OB = OP + (size_t)NN * 3;
  const size_t OE = OB + (size_t)NN;
  const size_t OA = OE + (size_t)2 * EE;

  char* w = (char*)d_ws;
  size_t woff = 0;
  auto alloc = [&](size_t bytes) -> void* {
    void* p = w + woff;
    woff += (bytes + 255) & ~(size_t)255;
    return p;
  };
  // zeroed region (one memset)
  unsigned* rank    = (unsigned*)alloc((size_t)RAWCAP * 4);
  unsigned* cnt     = (unsigned*)alloc((size_t)(NN + 1) * 4);
  ull* desc0        = (ull*)alloc(4096 * 8);
  ull* desc1        = (ull*)alloc(4096 * 8);
  ull* desc2        = (ull*)alloc(4096 * 8);
  ull* desc3        = (ull*)alloc(4096 * 8);
  size_t zero_bytes = woff;
  // written-before-read region
  int* cluster      = (int*)alloc((size_t)NN * 4);
  int* nlist        = (int*)alloc((size_t)NN * 4);
  unsigned* node_off= (unsigned*)alloc((size_t)(NN + 2) * 4);
  unsigned* mat     = (unsigned*)alloc((size_t)NSB * NBUCK * 4);
  unsigned* matT    = (unsigned*)alloc((size_t)NSB * NBUCK * 4);
  unsigned* hdr     = (unsigned*)alloc(256);
  ull* keys         = (ull*)alloc((size_t)EE * 8);

  hipMemsetAsync(d_ws, 0, zero_bytes, stream);

  init_hdr_k<<<1, 64, 0, stream>>>(hdr);
  minmax_k<<<128, 256, 0, stream>>>(pos, hdr);
  dims_k<<<1, 64, 0, stream>>>(hdr);
  raw_k<<<(NN + 255) / 256, 256, 0, stream>>>(pos, batch, hdr, cluster, rank);

  auto scan1 = [&](const unsigned* in_, unsigned* out_, int ntot,
                   unsigned* total_out, ull* d_) {
    int nb = (ntot + 1023) / 1024;
    scan_lb_k<<<nb, 256, 0, stream>>>(in_, out_, ntot, total_out, d_, nb);
  };
  scan1(rank, rank, RAWCAP, hdr + 8, desc0);   // rank[raw]=cluster id; total->ncl

  node_cnt_k<<<(NN + 255) / 256, 256, 0, stream>>>(rank, cluster, cnt);
  scan1(cnt, node_off, NN + 1, nullptr, desc1);
  node_scatter_k<<<(NN + 255) / 256, 256, 0, stream>>>(cluster, node_off, nlist);
  cluster_reduce_k<<<2048, 256, 0, stream>>>(x, pos, batch, nlist, node_off, hdr,
                                             out + OX, out + OP, out + OB);
  node_tail_k<<<2048, 256, 0, stream>>>(hdr, out + OX, out + OP, out + OB);

  coarse_cnt_k<<<NSB, 512, 0, stream>>>(ei, cluster, mat);
  transpose_k<<<(NSB * NBUCK + 255) / 256, 256, 0, stream>>>(mat, matT);
  scan1(matT, matT, NSB * NBUCK, hdr + 11, desc2);   // chunk offsets; total->Etot
  coarse_scatter_k<<<NSB, 512, 0, stream>>>(ei, cluster, matT, keys);
  grp_emit_k<<<NBUCK, 256, 0, stream>>>(keys, matT, hdr, desc3, ea,
                                        out + OE, out + OE + EE, out + OA);
  tail_fill_k<<<512, 256, 0, stream>>>(hdr, out + OE, out + OE + EE, out + OA);
}